// Round 7
// baseline (102.014 us; speedup 1.0000x reference)
//
#include <hip/hip_runtime.h>

#define B_ROWS   262144
#define C_DIM    128
#define K_CLS    128
#define PAD_R    2048
#define PAD2     4096
#define QSPLIT   4
#define QROWS    (PAD_R / QSPLIT)
#define EPS_F    1e-8f
#define CHUNK    1024
#define G_CHUNKS 256

typedef float f32x4  __attribute__((ext_vector_type(4)));
typedef short bf16x8 __attribute__((ext_vector_type(8)));

__device__ __forceinline__ unsigned f2bf(float f) {
  unsigned u = __float_as_uint(f);
  return (u + 0x7fffu + ((u >> 16) & 1u)) >> 16;   // RNE bf16
}
__device__ __forceinline__ unsigned packbf(float a, float b) {
  return f2bf(a) | (f2bf(b) << 16);
}
__device__ __forceinline__ int swzkey(int c) { return (c ^ (c >> 2)) & 7; }

// ---------------- histogram over 1024-row chunks (+ numden zero) ----------------
__global__ __launch_bounds__(256) void hist_kernel(const int* __restrict__ y,
                                                   int* __restrict__ hist,
                                                   float* __restrict__ numden) {
  __shared__ int h[K_CLS];
  int g = blockIdx.x, tid = threadIdx.x;
  if (g == 0 && tid < 64) numden[tid] = 0.f;
  if (tid < K_CLS) h[tid] = 0;
  __syncthreads();
  for (int j = tid; j < CHUNK; j += 256) atomicAdd(&h[y[g * CHUNK + j]], 1);
  __syncthreads();
  if (tid < K_CLS) hist[g * K_CLS + tid] = h[tid];
}

// ---------------- per-class exclusive scan over chunks ----------------
__global__ __launch_bounds__(256) void scan_kernel(int* __restrict__ hist,
                                                   int* __restrict__ counts) {
  __shared__ int s[G_CHUNKS];
  int k = blockIdx.x, g = threadIdx.x;
  int v = hist[g * K_CLS + k];
  s[g] = v;
  __syncthreads();
  for (int off = 1; off < G_CHUNKS; off <<= 1) {
    int t = (g >= off) ? s[g - off] : 0;
    __syncthreads();
    s[g] += t;
    __syncthreads();
  }
  hist[g * K_CLS + k] = s[g] - v;          // exclusive prefix
  if (g == G_CHUNKS - 1) counts[k] = s[g]; // total count
}

// ---------------- parallel stable ranks -> ord[] (no atomics, no x) ----------------
__global__ __launch_bounds__(256) void rank_kernel(const int* __restrict__ y,
                                                   const int* __restrict__ hist,
                                                   int* __restrict__ ord) {
  __shared__ unsigned short cnt_sub[16][K_CLS];  // per-subchunk per-class counts -> prefixes
  __shared__ int offs[K_CLS];
  const int g = blockIdx.x, tid = threadIdx.x;
  const int lane = tid & 63, w = tid >> 6;
  if (tid < K_CLS) offs[tid] = hist[g * K_CLS + tid];
  {
    unsigned int* cz = (unsigned int*)cnt_sub;
    for (int i = tid; i < 16 * K_CLS / 2; i += 256) cz[i] = 0;
  }
  __syncthreads();

  int yv[4], rig[4];
  #pragma unroll
  for (int i = 0; i < 4; ++i) {
    const int s = w * 4 + i;
    const int yy = y[g * CHUNK + s * 64 + lane];
    unsigned long long m = ~0ULL;
    #pragma unroll
    for (int b = 0; b < 7; ++b) {
      unsigned long long bb = __ballot((yy >> b) & 1);
      m &= ((yy >> b) & 1) ? bb : ~bb;
    }
    const unsigned long long lt = (1ULL << lane) - 1ULL;
    rig[i] = (int)__popcll(m & lt);
    yv[i] = yy;
    const int leader = __ffsll((long long)m) - 1;
    if (lane == leader) cnt_sub[s][yy] = (unsigned short)__popcll(m);
  }
  __syncthreads();

  if (tid < K_CLS) {                       // exclusive prefix over 16 subchunks, per class
    int run = 0;
    #pragma unroll
    for (int s = 0; s < 16; ++s) {
      int t = cnt_sub[s][tid];
      cnt_sub[s][tid] = (unsigned short)run;
      run += t;
    }
  }
  __syncthreads();

  #pragma unroll
  for (int i = 0; i < 4; ++i) {
    const int s = w * 4 + i;
    const int k = yv[i];
    const int R = offs[k] + (int)cnt_sub[s][k] + rig[i];
    if (R < PAD2) ord[k * PAD2 + R] = g * CHUNK + s * 64 + lane;
  }
}

// ---------------- per-class X^T X via MFMA, 4 blocks/class ----------------
// LDS tile buffer: 128 c-rows x 32 u32 (t-pairs), XOR-swizzled in 16B groups:
//   addr_u32(c,u) = c*32 + (((u>>2) ^ swzkey(c)) << 2 | (u&3))
__global__ __launch_bounds__(512, 4) void gemm_kernel(const float* __restrict__ x,
                                                      const int* __restrict__ ord,
                                                      const int* __restrict__ counts,
                                                      float* __restrict__ spart,
                                                      float* __restrict__ sums_part,
                                                      float* __restrict__ sqs_part,
                                                      float* __restrict__ ovfs_part) {
  __shared__ unsigned int lds[2 * C_DIM * 32];   // 32 KB double-buffered
  __shared__ int ord_l[QROWS];                   // 2 KB staged indices
  const int blk = blockIdx.x;
  const int k = blk >> 2, quarter = blk & 3;
  const int cnt_full = counts[k];
  const int T = cnt_full < PAD_R ? cnt_full : PAD_R;
  const int r_base = quarter * QROWS;
  const int rend = (T < r_base + QROWS) ? T : (r_base + QROWS);
  const int nr = rend - r_base;
  const int nt = (nr > 0) ? ((nr + 63) >> 6) : 0;

  const int tid = threadIdx.x;
  const int lane = tid & 63;
  const int w = tid >> 6;                  // wave 0..7
  const int wr = w >> 1, wc = w & 1;       // wave tile: rows wr*32.., cols wc*64..
  const int l5 = lane >> 5;                // half-wave select
  const int lc = lane & 31;                // 16B column slice

  f32x4 acc[2][4];
  #pragma unroll
  for (int i = 0; i < 2; ++i)
    #pragma unroll
    for (int j = 0; j < 4; ++j) acc[i][j] = (f32x4){0.f, 0.f, 0.f, 0.f};
  float sum4[4] = {0.f, 0.f, 0.f, 0.f}, sq4[4] = {0.f, 0.f, 0.f, 0.f};

  const int* ordk = ord + k * PAD2;

  for (int i = tid; i < QROWS; i += 512) {
    int vi = ordk[r_base + i];
    ord_l[i] = ((unsigned)vi < B_ROWS) ? vi : 0;   // clamp stale/poison values
  }
  __syncthreads();

  // lane's quartet for tile t: local rows rr..rr+3, rr = t*64 + w*8 + l5*4
  auto load_tile = [&](int t, f32x4* vv) {
    const int rr = t * 64 + w * 8 + l5 * 4;
    const int4 idx = *(const int4*)(&ord_l[rr]);
    const int rg = r_base + rr;
    const size_t co = (size_t)(lc << 2);
    const f32x4 z = (f32x4){0.f, 0.f, 0.f, 0.f};
    vv[0] = (rg + 0 < rend) ? *(const f32x4*)(x + (size_t)idx.x * C_DIM + co) : z;
    vv[1] = (rg + 1 < rend) ? *(const f32x4*)(x + (size_t)idx.y * C_DIM + co) : z;
    vv[2] = (rg + 2 < rend) ? *(const f32x4*)(x + (size_t)idx.z * C_DIM + co) : z;
    vv[3] = (rg + 3 < rend) ? *(const f32x4*)(x + (size_t)idx.w * C_DIM + co) : z;
  };

  // stats + pack into LDS; pair index u = w*4 + l5*2 + jp  (u>>2 == w)
  auto write_tile = [&](unsigned int* buf, const f32x4* vv) {
    #pragma unroll
    for (int j = 0; j < 4; ++j)
      #pragma unroll
      for (int e = 0; e < 4; ++e) { float t = vv[j][e]; sum4[e] += t; sq4[e] += t * t; }
    #pragma unroll
    for (int jp = 0; jp < 2; ++jp) {
      const int us = l5 * 2 + jp;
      #pragma unroll
      for (int e = 0; e < 4; ++e) {
        const int c = (lc << 2) + e;
        buf[c * 32 + (((w ^ swzkey(c)) << 2) | us)] =
            packbf(vv[jp * 2][e], vv[jp * 2 + 1][e]);
      }
    }
  };

  auto compute_tile = [&](const unsigned int* buf) {
    const int q2 = lane >> 4;
    const int fr = lane & 15;
    #pragma unroll
    for (int s = 0; s < 2; ++s) {          // two K=32 steps per 64-row tile
      const int g = s * 4 + q2;
      bf16x8 afr[2], bfr[4];
      #pragma unroll
      for (int mi = 0; mi < 2; ++mi) {
        const int c = wr * 32 + mi * 16 + fr;
        afr[mi] = *(const bf16x8*)(&buf[c * 32 + ((g ^ swzkey(c)) << 2)]);
      }
      #pragma unroll
      for (int ni = 0; ni < 4; ++ni) {
        const int d = wc * 64 + ni * 16 + fr;
        bfr[ni] = *(const bf16x8*)(&buf[d * 32 + ((g ^ swzkey(d)) << 2)]);
      }
      #pragma unroll
      for (int mi = 0; mi < 2; ++mi)
        #pragma unroll
        for (int ni = 0; ni < 4; ++ni)
          acc[mi][ni] = __builtin_amdgcn_mfma_f32_16x16x32_bf16(afr[mi], bfr[ni], acc[mi][ni], 0, 0, 0);
    }
  };

  // software pipeline: 1 barrier/tile, loads issued 2 tiles ahead, unroll x2
  f32x4 va[4], vb[4];
  if (nt > 0) { load_tile(0, va); write_tile(lds, va); }
  if (nt > 1) load_tile(1, va);
  __syncthreads();
  int cur = 0;
  for (int t = 0; t < nt; t += 2) {
    if (t + 1 < nt) write_tile(lds + (unsigned)(cur ^ 1) * (C_DIM * 32), va);
    if (t + 2 < nt) load_tile(t + 2, vb);
    compute_tile(lds + (unsigned)cur * (C_DIM * 32));
    __syncthreads();
    cur ^= 1;
    if (t + 1 >= nt) break;
    if (t + 2 < nt) write_tile(lds + (unsigned)(cur ^ 1) * (C_DIM * 32), vb);
    if (t + 3 < nt) load_tile(t + 3, va);
    compute_tile(lds + (unsigned)cur * (C_DIM * 32));
    __syncthreads();
    cur ^= 1;
  }

  // ---- overflow rows (r >= PAD_R): full-stat contribution only, coalesced ----
  float osum[4] = {0.f, 0.f, 0.f, 0.f}, osq[4] = {0.f, 0.f, 0.f, 0.f};
  const int colo = lc << 2;
  for (int r = PAD_R + quarter + ((tid >> 5) << 2); r < cnt_full; r += 64) {
    int row = ordk[r];
    f32x4 vv = *(const f32x4*)(x + (size_t)row * C_DIM + colo);
    #pragma unroll
    for (int e = 0; e < 4; ++e) { float t = vv[e]; osum[e] += t; osq[e] += t * t; }
  }

  // ---- epilogue: reduce trunc-sum / full-sq / ovf-sum, store partial S ----
  __syncthreads();
  float* red = (float*)lds;
  if (tid < 3 * C_DIM) red[tid] = 0.f;
  __syncthreads();
  #pragma unroll
  for (int e = 0; e < 4; ++e) {
    atomicAdd(&red[colo + e], sum4[e]);
    atomicAdd(&red[C_DIM + colo + e], sq4[e] + osq[e]);
    atomicAdd(&red[2 * C_DIM + colo + e], osum[e]);
  }
  __syncthreads();
  if (tid < C_DIM) {
    sums_part[(quarter * K_CLS + k) * C_DIM + tid] = red[tid];
    sqs_part [(quarter * K_CLS + k) * C_DIM + tid] = red[C_DIM + tid];
    ovfs_part[(quarter * K_CLS + k) * C_DIM + tid] = red[2 * C_DIM + tid];
  }
  float* sp = spart + (size_t)(quarter * K_CLS + k) * (C_DIM * C_DIM);
  #pragma unroll
  for (int mi = 0; mi < 2; ++mi)
    #pragma unroll
    for (int ni = 0; ni < 4; ++ni)
      #pragma unroll
      for (int r = 0; r < 4; ++r) {
        int c = wr * 32 + mi * 16 + ((lane >> 4) << 2) + r;
        int d = wc * 64 + ni * 16 + (lane & 15);
        sp[c * C_DIM + d] = acc[mi][ni][r];
      }
}

// ---------------- per-class analytic corr, off-diag^2 reduction ----------------
__global__ __launch_bounds__(512) void finalize_kernel(const float* __restrict__ spart,
                                                       const float* __restrict__ sums_part,
                                                       const float* __restrict__ sqs_part,
                                                       const float* __restrict__ ovfs_part,
                                                       const int* __restrict__ counts,
                                                       float* __restrict__ numden) {
  __shared__ float m_l[C_DIM], is_l[C_DIM], st_l[C_DIM];
  __shared__ float wred[8];
  int k = blockIdx.x, tid = threadIdx.x;
  int count = counts[k];
  float Tf = (float)(count < PAD_R ? count : PAD_R);
  if (tid < C_DIM) {
    float s_tr = 0.f, osum = 0.f, fsq = 0.f;
    #pragma unroll
    for (int j = 0; j < QSPLIT; ++j) {
      s_tr += sums_part[(j * K_CLS + k) * C_DIM + tid];
      osum += ovfs_part[(j * K_CLS + k) * C_DIM + tid];
      fsq  += sqs_part [(j * K_CLS + k) * C_DIM + tid];
    }
    float fsum = s_tr + osum;
    float cf = (float)count;
    float m = fsum / fmaxf(cf, 1.f);
    float var = (fsq - cf * m * m) / fmaxf(cf - 1.f, 1.f);
    m_l[tid] = m;
    is_l[tid] = rsqrtf(var + EPS_F);
    st_l[tid] = s_tr;
  }
  __syncthreads();
  float local = 0.f;
  for (int e4 = tid * 4; e4 < C_DIM * C_DIM; e4 += 512 * 4) {
    int c = e4 >> 7, d0 = e4 & 127;
    f32x4 sa = (f32x4){0.f, 0.f, 0.f, 0.f};
    #pragma unroll
    for (int j = 0; j < QSPLIT; ++j) {
      f32x4 sj = *(const f32x4*)(spart + (size_t)(j * K_CLS + k) * (C_DIM * C_DIM) + e4);
      #pragma unroll
      for (int e = 0; e < 4; ++e) sa[e] += sj[e];
    }
    #pragma unroll
    for (int e = 0; e < 4; ++e) {
      int d = d0 + e;
      float corr = is_l[c] * is_l[d] *
                   (sa[e] - m_l[c] * st_l[d] - m_l[d] * st_l[c] + Tf * m_l[c] * m_l[d]);
      if (c != d) local += corr * corr;
    }
  }
  for (int off = 32; off > 0; off >>= 1) local += __shfl_down(local, off);
  int lane = tid & 63, wid = tid >> 6;
  if (lane == 0) wred[wid] = local;
  __syncthreads();
  if (tid == 0 && count > 1) {
    float tot = 0.f;
    #pragma unroll
    for (int i = 0; i < 8; ++i) tot += wred[i];
    atomicAdd(&numden[0], tot * (1.f / (float)(C_DIM * (C_DIM - 1))));
    atomicAdd(&numden[1], (float)count);
  }
}

__global__ void div_kernel(const float* __restrict__ numden, float* __restrict__ out) {
  if (threadIdx.x == 0 && blockIdx.x == 0)
    out[0] = numden[1] > 0.f ? numden[0] / numden[1] : 0.f;
}

// ---------------- workspace layout (ws_size = 512 MB, plenty) ----------------
// [0,256)            numden
// [256, +128K)       hist
// [131328, +512)     counts
// [132096, +2M)      ord (128 * 4096 * 4)
// [2229248, +256K)   sums_part (4 * 128 * 128 * 4)
// [2491392, +256K)   sqs_part
// [2753536, +256K)   ovfs_part
// [3015680, +32M)    spart (4 * 128 * 64KB)
extern "C" void kernel_launch(void* const* d_in, const int* in_sizes, int n_in,
                              void* d_out, int out_size, void* d_ws, size_t ws_size,
                              hipStream_t stream) {
  (void)in_sizes; (void)n_in; (void)out_size; (void)ws_size;
  const float* x = (const float*)d_in[0];
  const int*   y = (const int*)d_in[1];
  float* out = (float*)d_out;
  char* ws = (char*)d_ws;

  float* numden    = (float*)(ws + 0);
  int*   hist      = (int*)(ws + 256);
  int*   counts    = (int*)(ws + 131328);
  int*   ord       = (int*)(ws + 132096);
  float* sums_part = (float*)(ws + 2229248);
  float* sqs_part  = (float*)(ws + 2491392);
  float* ovfs_part = (float*)(ws + 2753536);
  float* spart     = (float*)(ws + 3015680);

  hist_kernel<<<G_CHUNKS, 256, 0, stream>>>(y, hist, numden);
  scan_kernel<<<K_CLS, 256, 0, stream>>>(hist, counts);
  rank_kernel<<<G_CHUNKS, 256, 0, stream>>>(y, hist, ord);
  gemm_kernel<<<QSPLIT * K_CLS, 512, 0, stream>>>(x, ord, counts, spart, sums_part,
                                                  sqs_part, ovfs_part);
  finalize_kernel<<<K_CLS, 512, 0, stream>>>(spart, sums_part, sqs_part, ovfs_part,
                                             counts, numden);
  div_kernel<<<1, 64, 0, stream>>>(numden, out);
}

// Round 8
// 70.517 us; speedup vs baseline: 1.4467x; 1.4467x over previous
//
#include <hip/hip_runtime.h>

#define B_ROWS   262144
#define C_DIM    128
#define K_CLS    128
#define PAD_R    2048
#define PAD2     4096
#define QSPLIT   4
#define QROWS    (PAD_R / QSPLIT)
#define TROWS    32
#define EPS_F    1e-8f
#define CHUNK    1024
#define G_CHUNKS 256

typedef float f32x4  __attribute__((ext_vector_type(4)));
typedef short bf16x8 __attribute__((ext_vector_type(8)));

__device__ __forceinline__ unsigned f2bf(float f) {
  unsigned u = __float_as_uint(f);
  return (u + 0x7fffu + ((u >> 16) & 1u)) >> 16;   // RNE bf16
}
__device__ __forceinline__ unsigned packbf(float a, float b) {
  return f2bf(a) | (f2bf(b) << 16);
}
__device__ __forceinline__ int swzkey2(int c) { return (c ^ (c >> 2)) & 3; }

// ---------------- histogram over 1024-row chunks (+ numden zero) ----------------
__global__ __launch_bounds__(256) void hist_kernel(const int* __restrict__ y,
                                                   int* __restrict__ hist,
                                                   float* __restrict__ numden) {
  __shared__ int h[K_CLS];
  int g = blockIdx.x, tid = threadIdx.x;
  if (g == 0 && tid < 64) numden[tid] = 0.f;
  if (tid < K_CLS) h[tid] = 0;
  __syncthreads();
  for (int j = tid; j < CHUNK; j += 256) atomicAdd(&h[y[g * CHUNK + j]], 1);
  __syncthreads();
  if (tid < K_CLS) hist[g * K_CLS + tid] = h[tid];
}

// ---------------- per-class exclusive scan over chunks ----------------
__global__ __launch_bounds__(256) void scan_kernel(int* __restrict__ hist,
                                                   int* __restrict__ counts) {
  __shared__ int s[G_CHUNKS];
  int k = blockIdx.x, g = threadIdx.x;
  int v = hist[g * K_CLS + k];
  s[g] = v;
  __syncthreads();
  for (int off = 1; off < G_CHUNKS; off <<= 1) {
    int t = (g >= off) ? s[g - off] : 0;
    __syncthreads();
    s[g] += t;
    __syncthreads();
  }
  hist[g * K_CLS + k] = s[g] - v;          // exclusive prefix
  if (g == G_CHUNKS - 1) counts[k] = s[g]; // total count
}

// ---------------- parallel stable ranks -> ord[] (no atomics, no x) ----------------
__global__ __launch_bounds__(256) void rank_kernel(const int* __restrict__ y,
                                                   const int* __restrict__ hist,
                                                   int* __restrict__ ord) {
  __shared__ unsigned short cnt_sub[16][K_CLS];  // per-subchunk per-class counts -> prefixes
  __shared__ int offs[K_CLS];
  const int g = blockIdx.x, tid = threadIdx.x;
  const int lane = tid & 63, w = tid >> 6;
  if (tid < K_CLS) offs[tid] = hist[g * K_CLS + tid];
  {
    unsigned int* cz = (unsigned int*)cnt_sub;
    for (int i = tid; i < 16 * K_CLS / 2; i += 256) cz[i] = 0;
  }
  __syncthreads();

  int yv[4], rig[4];
  #pragma unroll
  for (int i = 0; i < 4; ++i) {
    const int s = w * 4 + i;
    const int yy = y[g * CHUNK + s * 64 + lane];
    unsigned long long m = ~0ULL;
    #pragma unroll
    for (int b = 0; b < 7; ++b) {
      unsigned long long bb = __ballot((yy >> b) & 1);
      m &= ((yy >> b) & 1) ? bb : ~bb;
    }
    const unsigned long long lt = (1ULL << lane) - 1ULL;
    rig[i] = (int)__popcll(m & lt);
    yv[i] = yy;
    const int leader = __ffsll((long long)m) - 1;
    if (lane == leader) cnt_sub[s][yy] = (unsigned short)__popcll(m);
  }
  __syncthreads();

  if (tid < K_CLS) {                       // exclusive prefix over 16 subchunks, per class
    int run = 0;
    #pragma unroll
    for (int s = 0; s < 16; ++s) {
      int t = cnt_sub[s][tid];
      cnt_sub[s][tid] = (unsigned short)run;
      run += t;
    }
  }
  __syncthreads();

  #pragma unroll
  for (int i = 0; i < 4; ++i) {
    const int s = w * 4 + i;
    const int k = yv[i];
    const int R = offs[k] + (int)cnt_sub[s][k] + rig[i];
    if (R < PAD2) ord[k * PAD2 + R] = g * CHUNK + s * 64 + lane;
  }
}

// ---------------- per-class X^T X via MFMA, 4 blocks/class, 32-row tiles ----------------
// LDS tile buffer: 128 c-rows x 16 u32 (t-pairs p=0..15), XOR-swizzled in 16B groups:
//   addr_u32(c,p) = c*16 + (((p>>2) ^ swzkey2(c)) << 2 | (p&3))
// Per thread per tile: 2 x-rows (2p, 2p+1), one 16B col slice -> 2 f32x4 loads, 4 u32 LDS writes.
__global__ __launch_bounds__(512, 4) void gemm_kernel(const float* __restrict__ x,
                                                      const int* __restrict__ ord,
                                                      const int* __restrict__ counts,
                                                      float* __restrict__ spart,
                                                      float* __restrict__ sums_part,
                                                      float* __restrict__ sqs_part,
                                                      float* __restrict__ ovfs_part) {
  __shared__ unsigned int lds[2 * C_DIM * 16];   // 16 KB double-buffered
  __shared__ int ord_l[QROWS];                   // 2 KB staged indices
  const int blk = blockIdx.x;
  const int k = blk >> 2, quarter = blk & 3;
  const int cnt_full = counts[k];
  const int T = cnt_full < PAD_R ? cnt_full : PAD_R;
  const int r_base = quarter * QROWS;
  const int rend = (T < r_base + QROWS) ? T : (r_base + QROWS);
  const int nr = rend - r_base;
  const int nt = (nr > 0) ? ((nr + TROWS - 1) / TROWS) : 0;

  const int tid = threadIdx.x;
  const int lane = tid & 63;
  const int w = tid >> 6;                  // wave 0..7
  const int wr = w >> 1, wc = w & 1;       // wave tile: rows wr*32.., cols wc*64..
  const int p = tid >> 5;                  // pair-row 0..15
  const int lc = tid & 31;                 // 16B column slice

  f32x4 acc[2][4];
  #pragma unroll
  for (int i = 0; i < 2; ++i)
    #pragma unroll
    for (int j = 0; j < 4; ++j) acc[i][j] = (f32x4){0.f, 0.f, 0.f, 0.f};
  float sum4[4] = {0.f, 0.f, 0.f, 0.f}, sq4[4] = {0.f, 0.f, 0.f, 0.f};

  const int* ordk = ord + k * PAD2;

  if (tid < QROWS) {
    int vi = ordk[r_base + tid];
    ord_l[tid] = ((unsigned)vi < B_ROWS) ? vi : 0;   // clamp stale/poison values
  }
  __syncthreads();

  // lane's row pair for tile t: local rows 2p, 2p+1 within [t*32, t*32+32)
  auto load_tile = [&](int t, f32x4* vv) {
    const int rr = t * TROWS + 2 * p;
    const int2 idx = *(const int2*)(&ord_l[rr]);
    const int rg = r_base + rr;
    const size_t co = (size_t)(lc << 2);
    const f32x4 z = (f32x4){0.f, 0.f, 0.f, 0.f};
    vv[0] = (rg + 0 < rend) ? *(const f32x4*)(x + (size_t)idx.x * C_DIM + co) : z;
    vv[1] = (rg + 1 < rend) ? *(const f32x4*)(x + (size_t)idx.y * C_DIM + co) : z;
  };

  // stats + pack into LDS at pair-slot p
  auto write_tile = [&](unsigned int* buf, const f32x4* vv) {
    #pragma unroll
    for (int j = 0; j < 2; ++j)
      #pragma unroll
      for (int e = 0; e < 4; ++e) { float t = vv[j][e]; sum4[e] += t; sq4[e] += t * t; }
    #pragma unroll
    for (int e = 0; e < 4; ++e) {
      const int c = (lc << 2) + e;
      buf[c * 16 + ((((p >> 2) ^ swzkey2(c)) << 2) | (p & 3))] = packbf(vv[0][e], vv[1][e]);
    }
  };

  auto compute_tile = [&](const unsigned int* buf) {
    const int g = lane >> 4;               // k-group: pairs 4g..4g+3 (rows 8g..8g+7)
    const int fr = lane & 15;
    bf16x8 afr[2], bfr[4];
    #pragma unroll
    for (int mi = 0; mi < 2; ++mi) {
      const int c = wr * 32 + mi * 16 + fr;
      afr[mi] = *(const bf16x8*)(&buf[c * 16 + ((g ^ swzkey2(c)) << 2)]);
    }
    #pragma unroll
    for (int ni = 0; ni < 4; ++ni) {
      const int d = wc * 64 + ni * 16 + fr;
      bfr[ni] = *(const bf16x8*)(&buf[d * 16 + ((g ^ swzkey2(d)) << 2)]);
    }
    #pragma unroll
    for (int mi = 0; mi < 2; ++mi)
      #pragma unroll
      for (int ni = 0; ni < 4; ++ni)
        acc[mi][ni] = __builtin_amdgcn_mfma_f32_16x16x32_bf16(afr[mi], bfr[ni], acc[mi][ni], 0, 0, 0);
  };

  // software pipeline: 1 barrier/tile, loads 2 tiles ahead, unroll x2, slim registers
  f32x4 va[2], vb[2];
  if (nt > 0) { load_tile(0, va); write_tile(lds, va); }
  if (nt > 1) load_tile(1, vb);
  __syncthreads();
  int cur = 0;
  for (int t = 0; t < nt; t += 2) {
    if (t + 1 < nt) write_tile(lds + (unsigned)(cur ^ 1) * (C_DIM * 16), vb);
    if (t + 2 < nt) load_tile(t + 2, va);
    compute_tile(lds + (unsigned)cur * (C_DIM * 16));
    __syncthreads();
    cur ^= 1;
    if (t + 1 >= nt) break;
    if (t + 2 < nt) write_tile(lds + (unsigned)(cur ^ 1) * (C_DIM * 16), va);
    if (t + 3 < nt) load_tile(t + 3, vb);
    compute_tile(lds + (unsigned)cur * (C_DIM * 16));
    __syncthreads();
    cur ^= 1;
  }

  // ---- overflow rows (r >= PAD_R): full-stat contribution only, coalesced ----
  float osum[4] = {0.f, 0.f, 0.f, 0.f}, osq[4] = {0.f, 0.f, 0.f, 0.f};
  const int colo = lc << 2;
  for (int r = PAD_R + quarter + (p << 2); r < cnt_full; r += 64) {
    int row = ordk[r];
    f32x4 vv = *(const f32x4*)(x + (size_t)row * C_DIM + colo);
    #pragma unroll
    for (int e = 0; e < 4; ++e) { float t = vv[e]; osum[e] += t; osq[e] += t * t; }
  }

  // ---- epilogue: reduce trunc-sum / full-sq / ovf-sum, store partial S ----
  __syncthreads();
  float* red = (float*)lds;
  if (tid < 3 * C_DIM) red[tid] = 0.f;
  __syncthreads();
  #pragma unroll
  for (int e = 0; e < 4; ++e) {
    atomicAdd(&red[colo + e], sum4[e]);
    atomicAdd(&red[C_DIM + colo + e], sq4[e] + osq[e]);
    atomicAdd(&red[2 * C_DIM + colo + e], osum[e]);
  }
  __syncthreads();
  if (tid < C_DIM) {
    sums_part[(quarter * K_CLS + k) * C_DIM + tid] = red[tid];
    sqs_part [(quarter * K_CLS + k) * C_DIM + tid] = red[C_DIM + tid];
    ovfs_part[(quarter * K_CLS + k) * C_DIM + tid] = red[2 * C_DIM + tid];
  }
  float* sp = spart + (size_t)(quarter * K_CLS + k) * (C_DIM * C_DIM);
  #pragma unroll
  for (int mi = 0; mi < 2; ++mi)
    #pragma unroll
    for (int ni = 0; ni < 4; ++ni)
      #pragma unroll
      for (int r = 0; r < 4; ++r) {
        int c = wr * 32 + mi * 16 + ((lane >> 4) << 2) + r;
        int d = wc * 64 + ni * 16 + (lane & 15);
        sp[c * C_DIM + d] = acc[mi][ni][r];
      }
}

// ---------------- per-class analytic corr, off-diag^2 reduction ----------------
__global__ __launch_bounds__(512) void finalize_kernel(const float* __restrict__ spart,
                                                       const float* __restrict__ sums_part,
                                                       const float* __restrict__ sqs_part,
                                                       const float* __restrict__ ovfs_part,
                                                       const int* __restrict__ counts,
                                                       float* __restrict__ numden) {
  __shared__ float m_l[C_DIM], is_l[C_DIM], st_l[C_DIM];
  __shared__ float wred[8];
  int k = blockIdx.x, tid = threadIdx.x;
  int count = counts[k];
  float Tf = (float)(count < PAD_R ? count : PAD_R);
  if (tid < C_DIM) {
    float s_tr = 0.f, osum = 0.f, fsq = 0.f;
    #pragma unroll
    for (int j = 0; j < QSPLIT; ++j) {
      s_tr += sums_part[(j * K_CLS + k) * C_DIM + tid];
      osum += ovfs_part[(j * K_CLS + k) * C_DIM + tid];
      fsq  += sqs_part [(j * K_CLS + k) * C_DIM + tid];
    }
    float fsum = s_tr + osum;
    float cf = (float)count;
    float m = fsum / fmaxf(cf, 1.f);
    float var = (fsq - cf * m * m) / fmaxf(cf - 1.f, 1.f);
    m_l[tid] = m;
    is_l[tid] = rsqrtf(var + EPS_F);
    st_l[tid] = s_tr;
  }
  __syncthreads();
  float local = 0.f;
  for (int e4 = tid * 4; e4 < C_DIM * C_DIM; e4 += 512 * 4) {
    int c = e4 >> 7, d0 = e4 & 127;
    f32x4 sa = (f32x4){0.f, 0.f, 0.f, 0.f};
    #pragma unroll
    for (int j = 0; j < QSPLIT; ++j) {
      f32x4 sj = *(const f32x4*)(spart + (size_t)(j * K_CLS + k) * (C_DIM * C_DIM) + e4);
      #pragma unroll
      for (int e = 0; e < 4; ++e) sa[e] += sj[e];
    }
    #pragma unroll
    for (int e = 0; e < 4; ++e) {
      int d = d0 + e;
      float corr = is_l[c] * is_l[d] *
                   (sa[e] - m_l[c] * st_l[d] - m_l[d] * st_l[c] + Tf * m_l[c] * m_l[d]);
      if (c != d) local += corr * corr;
    }
  }
  for (int off = 32; off > 0; off >>= 1) local += __shfl_down(local, off);
  int lane = tid & 63, wid = tid >> 6;
  if (lane == 0) wred[wid] = local;
  __syncthreads();
  if (tid == 0 && count > 1) {
    float tot = 0.f;
    #pragma unroll
    for (int i = 0; i < 8; ++i) tot += wred[i];
    atomicAdd(&numden[0], tot * (1.f / (float)(C_DIM * (C_DIM - 1))));
    atomicAdd(&numden[1], (float)count);
  }
}

__global__ void div_kernel(const float* __restrict__ numden, float* __restrict__ out) {
  if (threadIdx.x == 0 && blockIdx.x == 0)
    out[0] = numden[1] > 0.f ? numden[0] / numden[1] : 0.f;
}

// ---------------- workspace layout (ws_size = 512 MB, plenty) ----------------
// [0,256)            numden
// [256, +128K)       hist
// [131328, +512)     counts
// [132096, +2M)      ord (128 * 4096 * 4)
// [2229248, +256K)   sums_part (4 * 128 * 128 * 4)
// [2491392, +256K)   sqs_part
// [2753536, +256K)   ovfs_part
// [3015680, +32M)    spart (4 * 128 * 64KB)
extern "C" void kernel_launch(void* const* d_in, const int* in_sizes, int n_in,
                              void* d_out, int out_size, void* d_ws, size_t ws_size,
                              hipStream_t stream) {
  (void)in_sizes; (void)n_in; (void)out_size; (void)ws_size;
  const float* x = (const float*)d_in[0];
  const int*   y = (const int*)d_in[1];
  float* out = (float*)d_out;
  char* ws = (char*)d_ws;

  float* numden    = (float*)(ws + 0);
  int*   hist      = (int*)(ws + 256);
  int*   counts    = (int*)(ws + 131328);
  int*   ord       = (int*)(ws + 132096);
  float* sums_part = (float*)(ws + 2229248);
  float* sqs_part  = (float*)(ws + 2491392);
  float* ovfs_part = (float*)(ws + 2753536);
  float* spart     = (float*)(ws + 3015680);

  hist_kernel<<<G_CHUNKS, 256, 0, stream>>>(y, hist, numden);
  scan_kernel<<<K_CLS, 256, 0, stream>>>(hist, counts);
  rank_kernel<<<G_CHUNKS, 256, 0, stream>>>(y, hist, ord);
  gemm_kernel<<<QSPLIT * K_CLS, 512, 0, stream>>>(x, ord, counts, spart, sums_part,
                                                  sqs_part, ovfs_part);
  finalize_kernel<<<K_CLS, 512, 0, stream>>>(spart, sums_part, sqs_part, ovfs_part,
                                             counts, numden);
  div_kernel<<<1, 64, 0, stream>>>(numden, out);
}